// Round 1
// 1203.383 us; speedup vs baseline: 1.0186x; 1.0186x over previous
//
#include <hip/hip_runtime.h>
#include <math.h>

#define B 1024
#define S 256
#define D 512
#define E 16
#define O 512

typedef __bf16 bf16x8 __attribute__((ext_vector_type(8)));
typedef __bf16 bf16x4 __attribute__((ext_vector_type(4)));
typedef float f32x4 __attribute__((ext_vector_type(4)));
typedef unsigned short u16x4 __attribute__((ext_vector_type(4)));
typedef unsigned short u16x8 __attribute__((ext_vector_type(8)));

__device__ inline unsigned short f2bf(float f) {
    unsigned int u = __float_as_uint(f);
    unsigned int r = u + 0x7FFFu + ((u >> 16) & 1u);   // RNE
    return (unsigned short)(r >> 16);
}

// ---------------------------------------------------------------------------
// Kernel 1b: We [E][D][O] fp32 -> Wt [E][O][D] bf16 (transpose so K is
// contiguous for the MFMA B-operand fragment reads).
// grid = E * (D/32) * (O/32) = 4096 blocks, 256 threads.
// ---------------------------------------------------------------------------
__global__ __launch_bounds__(256) void cast_transpose_We(
    const float* __restrict__ We, unsigned short* __restrict__ Wt)
{
    const int bid = blockIdx.x;
    const int ot = bid & 15;          // O/32
    const int dt = (bid >> 4) & 15;   // D/32
    const int e  = bid >> 8;

    __shared__ unsigned short tile[32][33];   // +1 pad

    const int r  = threadIdx.x >> 3;          // 0..31
    const int c4 = (threadIdx.x & 7) * 4;     // 0,4,..,28

    const float* src = We + (((size_t)e * D + dt * 32 + r) * O + ot * 32 + c4);
    float4 v = *(const float4*)src;
    tile[r][c4 + 0] = f2bf(v.x);
    tile[r][c4 + 1] = f2bf(v.y);
    tile[r][c4 + 2] = f2bf(v.z);
    tile[r][c4 + 3] = f2bf(v.w);
    __syncthreads();

    // write transposed: Wt[e][o=ot*32+r][d=dt*32+c4..+3] = tile[c4+j][r]
    u16x4 w;
    w.x = tile[c4 + 0][r];
    w.y = tile[c4 + 1][r];
    w.z = tile[c4 + 2][r];
    w.w = tile[c4 + 3][r];
    unsigned short* dst = Wt + (((size_t)e * O + ot * 32 + r) * D + dt * 32 + c4);
    *(u16x4*)dst = w;
}

// ---------------------------------------------------------------------------
// Kernel 1a: column partial sums over S, split 2 ways so we get 2048 blocks
// (8/CU) and deeper unroll (16 float4 loads in flight/wave) — the old single
// gate kernel was latency-bound (~2 KB in flight/CU).
// partial[b][p][d] = sum_{s in p*128..p*128+127} x[b][s][d]
// partial lives in the FIRST 4 MiB of d_out (scratch; moe_gemm overwrites all
// of out afterwards).
// ---------------------------------------------------------------------------
__global__ __launch_bounds__(256) void col_partial(
    const float* __restrict__ x, float* __restrict__ partial)
{
    const int blk = blockIdx.x;       // B*2
    const int p   = blk & 1;
    const int b   = blk >> 1;
    const int t   = threadIdx.x;
    const int h   = t >> 7;           // 0/1: which 64-row half of this 128-row slice
    const int d4  = (t & 127) * 4;

    const int s0 = p * 128 + h * 64;
    const float* xb = x + ((size_t)b * S + s0) * D + d4;

    float ax = 0.f, ay = 0.f, az = 0.f, aw = 0.f;
    #pragma unroll 16
    for (int s = 0; s < 64; ++s) {
        float4 v = *(const float4*)(xb + (size_t)s * D);
        ax += v.x; ay += v.y; az += v.z; aw += v.w;
    }

    __shared__ float red[D];
    if (h == 1) {
        red[d4 + 0] = ax; red[d4 + 1] = ay; red[d4 + 2] = az; red[d4 + 3] = aw;
    }
    __syncthreads();
    if (h == 0) {
        float4 o;
        o.x = ax + red[d4 + 0];
        o.y = ay + red[d4 + 1];
        o.z = az + red[d4 + 2];
        o.w = aw + red[d4 + 3];
        *(float4*)(partial + (((size_t)b * 2 + p) * D + d4)) = o;
    }
}

// ---------------------------------------------------------------------------
// Kernel 1c: finish gating. One block per batch: read 2 partial vectors,
// logits = mean @ Wg + bg -> softmax -> argmax. Tiny (4 KB/block + Wg in L2).
// ---------------------------------------------------------------------------
__global__ __launch_bounds__(256) void gate_finish(
    const float* __restrict__ partial, const float* __restrict__ Wg,
    const float* __restrict__ bg, float* __restrict__ gatep,
    int* __restrict__ idxp)
{
    const int b = blockIdx.x;
    const int t = threadIdx.x;

    const float* pb = partial + (size_t)b * 2 * D;
    const float sx = pb[2 * t]     + pb[D + 2 * t];
    const float sy = pb[2 * t + 1] + pb[D + 2 * t + 1];
    const float* wg0 = Wg + (size_t)(2 * t) * E;
    const float* wg1 = Wg + (size_t)(2 * t + 1) * E;
    float part[E];
    #pragma unroll
    for (int e = 0; e < E; ++e) part[e] = sx * wg0[e] + sy * wg1[e];

    // wave reduce (64 lanes)
    #pragma unroll
    for (int e = 0; e < E; ++e) {
        float v = part[e];
        for (int off = 32; off > 0; off >>= 1) v += __shfl_down(v, off);
        part[e] = v;
    }

    __shared__ float wred[4][E];
    const int wave = t >> 6, lane = t & 63;
    if (lane == 0) {
        #pragma unroll
        for (int e = 0; e < E; ++e) wred[wave][e] = part[e];
    }
    __syncthreads();

    if (t == 0) {
        float logits[E];
        #pragma unroll
        for (int e = 0; e < E; ++e)
            logits[e] = (wred[0][e] + wred[1][e] + wred[2][e] + wred[3][e])
                            * (1.0f / (float)S) + bg[e];
        float m = logits[0];
        int am = 0;
        #pragma unroll
        for (int e = 1; e < E; ++e)
            if (logits[e] > m) { m = logits[e]; am = e; }   // first max, like np.argmax
        float sum = 0.f;
        #pragma unroll
        for (int e = 0; e < E; ++e) sum += expf(logits[e] - m);
        gatep[b] = 1.0f / sum;    // softmax value at its own argmax
        idxp[b]  = am;
    }
}

// ---------------------------------------------------------------------------
// Kernel 2: per-batch GEMM  out[b] = gate[b] * (x[b] @ We[idx[b]] + be[idx[b]])
// 128x128 tile, BK=32, mfma_f32_16x16x32_bf16, 4 waves, 4x4 frags per wave.
// grid = B * 2 * 4 = 8192 blocks.
// XCD-bijective swizzle: HW round-robins consecutive blockIdx across the 8
// XCDs, which scattered the 4 nt-siblings (sharing an A-tile) over 4 private
// L2s -> 2.2x x over-fetch. Remap so each XCD gets 1024 consecutive logical
// blocks => all 8 tiles of a batch co-locate on one XCD's L2.
// ---------------------------------------------------------------------------
__global__ __launch_bounds__(256) void moe_gemm(
    const float* __restrict__ x, const unsigned short* __restrict__ Wt,
    const float* __restrict__ be, const float* __restrict__ gatep,
    const int* __restrict__ idxp, float* __restrict__ out)
{
    const int bid0 = blockIdx.x;                      // 8192 = 8 * 1024
    const int bid  = ((bid0 & 7) << 10) | (bid0 >> 3); // bijective XCD swizzle
    const int nt = bid & 3;
    const int mt = (bid >> 2) & 1;
    const int b  = bid >> 3;
    const int m0 = mt * 128;
    const int n0 = nt * 128;

    const int t    = threadIdx.x;
    const int lane = t & 63;
    const int wave = t >> 6;
    const int wr   = wave >> 1;   // 0..1
    const int wc   = wave & 1;    // 0..1

    const int   e    = idxp[b];
    const float gate = gatep[b];

    __shared__ unsigned short As[128 * 32];   // [m][k], k contiguous
    __shared__ unsigned short Bs[128 * 32];   // [n][k], k contiguous

    const float*          Ab = x  + ((size_t)b * S + m0) * D;
    const unsigned short* Bb = Wt + ((size_t)e * O + n0) * D;

    f32x4 acc[4][4];
    #pragma unroll
    for (int i = 0; i < 4; ++i)
        #pragma unroll
        for (int j = 0; j < 4; ++j)
            #pragma unroll
            for (int r = 0; r < 4; ++r) acc[i][j][r] = 0.0f;

    for (int kk = 0; kk < D; kk += 32) {
        __syncthreads();   // protect LDS from previous iteration's readers

        // stage B: bf16, 16B per thread x2 (128 rows x 32 k)
        #pragma unroll
        for (int i = 0; i < 2; ++i) {
            const int c  = i * 256 + t;
            const int n  = c >> 2;
            const int k8 = (c & 3) * 8;
            u16x8 w = *(const u16x8*)(Bb + (size_t)n * D + kk + k8);
            *(u16x8*)&Bs[c * 8] = w;
        }
        // stage A: fp32 -> bf16 convert (native cvt_pk), 4 x float4 per thread
        #pragma unroll
        for (int i = 0; i < 4; ++i) {
            const int c  = i * 256 + t;
            const int m  = c >> 3;
            const int k4 = (c & 7) * 4;
            float4 v = *(const float4*)(Ab + (size_t)m * D + kk + k4);
            bf16x4 w;
            w.x = (__bf16)v.x; w.y = (__bf16)v.y;
            w.z = (__bf16)v.z; w.w = (__bf16)v.w;
            *(bf16x4*)&As[m * 32 + k4] = w;
        }
        __syncthreads();

        // fragments: A lane layout m=lane&15, k=(lane>>4)*8+j ; B dual
        bf16x8 fa[4], fb[4];
        #pragma unroll
        for (int i = 0; i < 4; ++i) {
            const int r = wr * 64 + i * 16 + (lane & 15);
            fa[i] = *(const bf16x8*)&As[r * 32 + (lane >> 4) * 8];
            const int n = wc * 64 + i * 16 + (lane & 15);
            fb[i] = *(const bf16x8*)&Bs[n * 32 + (lane >> 4) * 8];
        }
        #pragma unroll
        for (int i = 0; i < 4; ++i)
            #pragma unroll
            for (int j = 0; j < 4; ++j)
                acc[i][j] = __builtin_amdgcn_mfma_f32_16x16x32_bf16(
                    fa[i], fb[j], acc[i][j], 0, 0, 0);
    }

    // epilogue: C/D layout col=lane&15, row=(lane>>4)*4+reg
    float* ob = out + (size_t)b * S * O;
    #pragma unroll
    for (int j = 0; j < 4; ++j) {
        const int col  = n0 + wc * 64 + j * 16 + (lane & 15);
        const float bias = be[(size_t)e * O + col];
        #pragma unroll
        for (int i = 0; i < 4; ++i) {
            const int row0 = m0 + wr * 64 + i * 16 + (lane >> 4) * 4;
            #pragma unroll
            for (int r = 0; r < 4; ++r)
                ob[(size_t)(row0 + r) * O + col] = gate * (acc[i][j][r] + bias);
        }
    }
}

// ---------------------------------------------------------------------------
extern "C" void kernel_launch(void* const* d_in, const int* in_sizes, int n_in,
                              void* d_out, int out_size, void* d_ws, size_t ws_size,
                              hipStream_t stream) {
    const float* x  = (const float*)d_in[0];
    const float* Wg = (const float*)d_in[1];
    const float* bg = (const float*)d_in[2];
    const float* We = (const float*)d_in[3];
    const float* be = (const float*)d_in[4];
    float* out = (float*)d_out;

    // workspace layout: Wt bf16 [E*O*D] (8 MiB) | gate f32 [B] | idx i32 [B]
    unsigned short* Wt = (unsigned short*)d_ws;
    float* gatep = (float*)((char*)d_ws + (size_t)E * O * D * sizeof(unsigned short));
    int*   idxp  = (int*)((char*)gatep + B * sizeof(float));

    // partial sums scratch: first 4 MiB of out (moe_gemm overwrites all of out)
    float* partial = out;

    cast_transpose_We<<<E * (D / 32) * (O / 32), 256, 0, stream>>>(We, Wt);
    col_partial<<<B * 2, 256, 0, stream>>>(x, partial);
    gate_finish<<<B, 256, 0, stream>>>(partial, Wg, bg, gatep, idxp);
    moe_gemm<<<B * 8, 256, 0, stream>>>(x, Wt, be, gatep, idxp, out);
}